// Round 2
// baseline (1082.360 us; speedup 1.0000x reference)
//
#include <hip/hip_runtime.h>
#include <hip/hip_bf16.h>

#define E_EDGES   1000000
#define TILE_E    32
#define N_TILES   (E_EDGES / TILE_E)   // 31250
#define IN_DIM_K  128
#define HID_N     256
#define BN_EPS_F  1e-5f
#define MAIN_GRID 2048

typedef __attribute__((ext_vector_type(4))) float f32x4;
typedef __attribute__((ext_vector_type(8))) short bf16x8;

__device__ __forceinline__ unsigned short f2bf(float f) {
    __hip_bfloat16 h = __float2bfloat16(f);
    return *reinterpret_cast<unsigned short*>(&h);
}
__device__ __forceinline__ unsigned pack2(float lo, float hi) {
    return (unsigned)f2bf(lo) | ((unsigned)f2bf(hi) << 16);
}

union FragU { uint4 u; bf16x8 v; unsigned w[4]; };

__global__ void zero_stats_kernel(float* g) {
    g[threadIdx.x] = 0.0f;   // 512 threads
}

__global__ void finalize_stats_kernel(const float* __restrict__ gstat,
                                      const float* __restrict__ gamma,
                                      const float* __restrict__ beta,
                                      float* __restrict__ nAB) {
    int c = threadIdx.x;     // 256 threads
    float inv_e = 1.0f / (float)E_EDGES;
    float mean = gstat[c] * inv_e;
    float var  = fmaxf(gstat[256 + c] * inv_e - mean * mean, 0.0f);
    float a = gamma[c] * rsqrtf(var + BN_EPS_F);
    nAB[c] = a;
    nAB[256 + c] = beta[c] - mean * a;
}

// 256 threads = 4 waves, all split along N (64 cols each).
// Tile: 32 edges x 256 channels. Each lane gathers its own A-fragment
// directly from global (no LDS staging, no barriers in STATS pass).
template <bool STATS>
__global__ __launch_bounds__(256, 4)
void hadamard_mlp_kernel(const float* __restrict__ nodes,
                         const int* __restrict__ eidx,
                         const float* __restrict__ W1,
                         const float* __restrict__ W2,
                         const float* __restrict__ b2p,
                         float* __restrict__ gstat,
                         const float* __restrict__ nAB,
                         float* __restrict__ y)
{
    __shared__ float s_red[2][128];   // ping-pong: 4 waves x 32 edges

    const int tid  = threadIdx.x;
    const int lane = tid & 63;
    const int wn   = tid >> 6;        // 0..3 (N split)
    const int l15  = lane & 15;
    const int l4   = lane >> 4;

    // ---- B fragments from W1 (f32 [128][256] row-major) ----
    bf16x8 bfrag[4][4];
    #pragma unroll
    for (int nt = 0; nt < 4; ++nt) {
        const int c = wn * 64 + nt * 16 + l15;
        #pragma unroll
        for (int kk = 0; kk < 4; ++kk) {
            const int kb = kk * 32 + 8 * l4;
            FragU t;
            #pragma unroll
            for (int j = 0; j < 4; ++j) {
                float w0 = W1[(kb + 2 * j    ) * HID_N + c];
                float w1 = W1[(kb + 2 * j + 1) * HID_N + c];
                t.w[j] = pack2(w0, w1);
            }
            bfrag[nt][kk] = t.v;
        }
    }

    float a_n[4], b_n[4], w2_n[4];
    if (!STATS) {
        #pragma unroll
        for (int nt = 0; nt < 4; ++nt) {
            const int c = wn * 64 + nt * 16 + l15;
            a_n[nt]  = nAB[c];
            b_n[nt]  = nAB[256 + c];
            w2_n[nt] = W2[c];
        }
    }
    const float b2v = b2p[0];

    float s1[4] = {0.f, 0.f, 0.f, 0.f};
    float s2[4] = {0.f, 0.f, 0.f, 0.f};

    // ---- prefetched edge indices for the current tile ----
    int cs0, cd0, cs1, cd1;
    {
        const int e0 = blockIdx.x * TILE_E + l15;
        cs0 = eidx[e0];
        cd0 = eidx[E_EDGES + e0];
        cs1 = eidx[e0 + 16];
        cd1 = eidx[E_EDGES + e0 + 16];
    }

    int pp = 0;
    for (int tile = blockIdx.x; tile < N_TILES; tile += gridDim.x) {
        const float* sp0 = nodes + (size_t)cs0 * IN_DIM_K + l4 * 8;
        const float* dp0 = nodes + (size_t)cd0 * IN_DIM_K + l4 * 8;
        const float* sp1 = nodes + (size_t)cs1 * IN_DIM_K + l4 * 8;
        const float* dp1 = nodes + (size_t)cd1 * IN_DIM_K + l4 * 8;

        f32x4 acc[2][4] = {};
        #pragma unroll
        for (int kk = 0; kk < 4; ++kk) {
            float4 sa0 = *reinterpret_cast<const float4*>(sp0 + kk * 32);
            float4 sb0 = *reinterpret_cast<const float4*>(sp0 + kk * 32 + 4);
            float4 da0 = *reinterpret_cast<const float4*>(dp0 + kk * 32);
            float4 db0 = *reinterpret_cast<const float4*>(dp0 + kk * 32 + 4);
            float4 sa1 = *reinterpret_cast<const float4*>(sp1 + kk * 32);
            float4 sb1 = *reinterpret_cast<const float4*>(sp1 + kk * 32 + 4);
            float4 da1 = *reinterpret_cast<const float4*>(dp1 + kk * 32);
            float4 db1 = *reinterpret_cast<const float4*>(dp1 + kk * 32 + 4);

            FragU t0, t1;
            t0.w[0] = pack2(sa0.x * da0.x, sa0.y * da0.y);
            t0.w[1] = pack2(sa0.z * da0.z, sa0.w * da0.w);
            t0.w[2] = pack2(sb0.x * db0.x, sb0.y * db0.y);
            t0.w[3] = pack2(sb0.z * db0.z, sb0.w * db0.w);
            t1.w[0] = pack2(sa1.x * da1.x, sa1.y * da1.y);
            t1.w[1] = pack2(sa1.z * da1.z, sa1.w * da1.w);
            t1.w[2] = pack2(sb1.x * db1.x, sb1.y * db1.y);
            t1.w[3] = pack2(sb1.z * db1.z, sb1.w * db1.w);

            #pragma unroll
            for (int nt = 0; nt < 4; ++nt) {
                acc[0][nt] = __builtin_amdgcn_mfma_f32_16x16x32_bf16(
                    t0.v, bfrag[nt][kk], acc[0][nt], 0, 0, 0);
                acc[1][nt] = __builtin_amdgcn_mfma_f32_16x16x32_bf16(
                    t1.v, bfrag[nt][kk], acc[1][nt], 0, 0, 0);
            }
        }

        // ---- prefetch next tile's indices (hidden under epilogue) ----
        {
            const int ntile = tile + gridDim.x;
            if (ntile < N_TILES) {
                const int e0 = ntile * TILE_E + l15;
                cs0 = eidx[e0];
                cd0 = eidx[E_EDGES + e0];
                cs1 = eidx[e0 + 16];
                cd1 = eidx[E_EDGES + e0 + 16];
            }
        }

        if (STATS) {
            #pragma unroll
            for (int nt = 0; nt < 4; ++nt) {
                float t1s = 0.f, t2s = 0.f;
                #pragma unroll
                for (int mt = 0; mt < 2; ++mt)
                    #pragma unroll
                    for (int r = 0; r < 4; ++r) {
                        float v = acc[mt][nt][r];
                        t1s += v;
                        t2s += v * v;
                    }
                s1[nt] += t1s;
                s2[nt] += t2s;
            }
        } else {
            // y_e = sum_c relu(h*A + B) * W2[c]  (+ b2)
            float pw[2][4];
            #pragma unroll
            for (int mt = 0; mt < 2; ++mt)
                #pragma unroll
                for (int r = 0; r < 4; ++r) {
                    float acc_y = 0.f;
                    #pragma unroll
                    for (int nt = 0; nt < 4; ++nt) {
                        float z = acc[mt][nt][r] * a_n[nt] + b_n[nt];
                        z = fmaxf(z, 0.f);
                        acc_y += z * w2_n[nt];
                    }
                    pw[mt][r] = acc_y;
                }
            #pragma unroll
            for (int off = 1; off < 16; off <<= 1)
                #pragma unroll
                for (int mt = 0; mt < 2; ++mt)
                    #pragma unroll
                    for (int r = 0; r < 4; ++r)
                        pw[mt][r] += __shfl_xor(pw[mt][r], off, 64);
            if (l15 == 0) {
                #pragma unroll
                for (int mt = 0; mt < 2; ++mt)
                    #pragma unroll
                    for (int r = 0; r < 4; ++r)
                        s_red[pp][wn * 32 + mt * 16 + l4 * 4 + r] = pw[mt][r];
            }
            __syncthreads();
            if (tid < 32) {
                float yv = s_red[pp][tid] + s_red[pp][32 + tid]
                         + s_red[pp][64 + tid] + s_red[pp][96 + tid] + b2v;
                y[tile * TILE_E + tid] = yv;
            }
            pp ^= 1;
        }
    }

    if (STATS) {
        #pragma unroll
        for (int nt = 0; nt < 4; ++nt) {
            s1[nt] += __shfl_xor(s1[nt], 16, 64);
            s1[nt] += __shfl_xor(s1[nt], 32, 64);
            s2[nt] += __shfl_xor(s2[nt], 16, 64);
            s2[nt] += __shfl_xor(s2[nt], 32, 64);
        }
        if (l4 == 0) {
            #pragma unroll
            for (int nt = 0; nt < 4; ++nt) {
                const int c = wn * 64 + nt * 16 + l15;
                atomicAdd(&gstat[c],       s1[nt]);
                atomicAdd(&gstat[256 + c], s2[nt]);
            }
        }
    }
}

extern "C" void kernel_launch(void* const* d_in, const int* in_sizes, int n_in,
                              void* d_out, int out_size, void* d_ws, size_t ws_size,
                              hipStream_t stream) {
    const float* nodes = (const float*)d_in[0];
    const int*   eidx  = (const int*)d_in[1];
    const float* W1    = (const float*)d_in[2];
    // d_in[3] = b1 : analytically cancelled by batch-norm, unused
    const float* gamma = (const float*)d_in[4];
    const float* beta  = (const float*)d_in[5];
    const float* W2    = (const float*)d_in[6];
    const float* b2    = (const float*)d_in[7];

    float* ws    = (float*)d_ws;
    float* gstat = ws;          // 512 f32: sum_h[256], sumsq_h[256]
    float* nAB   = ws + 512;    // 512 f32: A[256], B[256]
    float* y     = (float*)d_out;

    zero_stats_kernel<<<1, 512, 0, stream>>>(gstat);
    hadamard_mlp_kernel<true><<<MAIN_GRID, 256, 0, stream>>>(
        nodes, eidx, W1, W2, b2, gstat, nAB, y);
    finalize_stats_kernel<<<1, 256, 0, stream>>>(gstat, gamma, beta, nAB);
    hadamard_mlp_kernel<false><<<MAIN_GRID, 256, 0, stream>>>(
        nodes, eidx, W1, W2, b2, gstat, nAB, y);
}